// Round 4
// baseline (5139.597 us; speedup 1.0000x reference)
//
#include <hip/hip_runtime.h>

// Net_87814901334404: B=512, CI=3, HW=28, K=7, C=1024, NH=16, L=12, T=17, M=B*T=8704
// Round 4: NO-LDS GEMM. Evidence: R1/R2/R3 all ~95us on QKV regardless of
// fetch/conflicts/barrier-count -> bound by per-iter vmcnt(0) barrier drain
// (m97 structural stall). Here K=1024 is skinny, B-panels (256KB) are
// L2-resident, A (17.8MB) is L3-resident: load fragments straight to VGPRs,
// register ping-pong double-buffer, zero barriers / zero LDS in the K-loop.

typedef unsigned short u16;
typedef short bfrag8 __attribute__((ext_vector_type(8)));
typedef float facc4 __attribute__((ext_vector_type(4)));

__device__ __forceinline__ u16 f2bf(float f) {
  union { float f; unsigned u; } x; x.f = f;
  unsigned r = x.u + 0x7fffu + ((x.u >> 16) & 1u);   // round-to-nearest-even
  return (u16)(r >> 16);
}
__device__ __forceinline__ float bf2f(u16 h) {
  union { unsigned u; float f; } x; x.u = ((unsigned)h) << 16;
  return x.f;
}

// ---------------------------------------------------------------------------
// GEMM: out[m,n] = sum_k A[m,k]*B[n,k]  (B row-major [N][K], out = A @ B^T)
// bf16 in, fp32 acc, mfma_f32_16x16x32_bf16 (A/B frag: idx=lane&15, k=quad*8+j;
// C/D: col=lane&15, row=quad*4+reg — learn_hip m89/m91).
// Each wave: independent 64x64 tile (block = 2x2 waves over 128x128).
// Fragments loaded directly global->VGPR (dwordx4 per frag), ping-pong
// double-buffered across BK=32 steps. K must be a multiple of 64.
// MODE 0: f32 out=acc(+bias); 1: bf16 out=acc(+bias); 2: f32 out+=acc(+bias);
// 3: f32 deconv scatter. blockIdx: x=N-tile, y=M-tile, z picks B0/B1/B2 and
// offsets out by z*zstride (QKV batching).
// ---------------------------------------------------------------------------
#define LOAD_SET(ab, bb)                                                    \
  {                                                                         \
    _Pragma("unroll")                                                       \
    for (int im = 0; im < 4; ++im) { ab[im] = *(const bfrag8*)ap[im]; ap[im] += 32; } \
    _Pragma("unroll")                                                       \
    for (int in = 0; in < 4; ++in) { bb[in] = *(const bfrag8*)bp[in]; bp[in] += 32; } \
  }

#define MFMA_SET(ab, bb)                                                    \
  {                                                                         \
    _Pragma("unroll")                                                       \
    for (int im = 0; im < 4; ++im)                                          \
      _Pragma("unroll")                                                     \
      for (int in = 0; in < 4; ++in)                                        \
        acc[im][in] = __builtin_amdgcn_mfma_f32_16x16x32_bf16(ab[im], bb[in], acc[im][in], 0, 0, 0); \
  }

template <int MODE>
__global__ __launch_bounds__(256) void gemm_bt(
    const u16* __restrict__ A, int lda,
    const u16* __restrict__ B0, const u16* __restrict__ B1, const u16* __restrict__ B2,
    int ldb, int K,
    void* __restrict__ outp, long long zstride, int ldo,
    const float* __restrict__ bias)
{
  const int n0 = blockIdx.x * 128;
  const int m0 = blockIdx.y * 128;
  const int z  = blockIdx.z;
  const u16* __restrict__ B = (z == 0) ? B0 : ((z == 1) ? B1 : B2);

  const int tid  = threadIdx.x;
  const int wave = tid >> 6;
  const int lane = tid & 63;
  const int wm   = (wave >> 1) * 64;
  const int wn   = (wave & 1) * 64;
  const int lrow = lane & 15;
  const int lquad = lane >> 4;

  facc4 acc[4][4] = {};

  const u16* ap[4]; const u16* bp[4];
#pragma unroll
  for (int im = 0; im < 4; ++im)
    ap[im] = A + (long long)(m0 + wm + im * 16 + lrow) * lda + lquad * 8;
#pragma unroll
  for (int in = 0; in < 4; ++in)
    bp[in] = B + (long long)(n0 + wn + in * 16 + lrow) * ldb + lquad * 8;

  bfrag8 a0[4], b0[4], a1[4], b1[4];
  const int nIter = K >> 5;                 // K/32, even (K % 64 == 0)

  LOAD_SET(a0, b0);
  for (int i = 1; i + 1 < nIter; i += 2) {
    LOAD_SET(a1, b1);
    MFMA_SET(a0, b0);
    LOAD_SET(a0, b0);
    MFMA_SET(a1, b1);
  }
  LOAD_SET(a1, b1);
  MFMA_SET(a0, b0);
  MFMA_SET(a1, b1);

#pragma unroll
  for (int in = 0; in < 4; ++in) {
    const int col = n0 + wn + in * 16 + lrow;
    const float bb = (MODE != 3 && bias) ? bias[col] : 0.0f;
#pragma unroll
    for (int im = 0; im < 4; ++im) {
#pragma unroll
      for (int r = 0; r < 4; ++r) {
        const int row = m0 + wm + im * 16 + lquad * 4 + r;
        const float v = acc[im][in][r] + bb;
        if (MODE == 0) {
          ((float*)outp)[(long long)row * ldo + col] = v;
        } else if (MODE == 1) {
          (((u16*)outp) + zstride * z)[(long long)row * ldo + col] = f2bf(v);
        } else if (MODE == 2) {
          ((float*)outp)[(long long)row * ldo + col] += v;
        } else {  // MODE 3: deconv scatter. row=b*17+s, col=d*49+hk*7+wk (<147)
          if (col < 147) {
            const int b = row / 17, s = row - b * 17;
            const int d = col / 49, rem = col - d * 49;
            const int hk = rem / 7, wk = rem - hk * 7;
            ((float*)outp)[(long long)((b * 3 + d) * 7 + hk) * 119 + s * 7 + wk] = v;
          }
        }
      }
    }
  }
}

// ---------------------------------------------------------------------------
// LayerNorm over C=1024: reads fp32 h row, writes bf16 normalized row.
// ---------------------------------------------------------------------------
__global__ __launch_bounds__(256) void ln_kernel(
    const float* __restrict__ h, const float* __restrict__ w,
    const float* __restrict__ b, u16* __restrict__ out)
{
  const long long row = blockIdx.x;
  const float* __restrict__ x = h + row * 1024;
  const int t = threadIdx.x;
  float v0 = x[t], v1 = x[t + 256], v2 = x[t + 512], v3 = x[t + 768];
  float s = v0 + v1 + v2 + v3;
  float q = v0 * v0 + v1 * v1 + v2 * v2 + v3 * v3;
  for (int o = 32; o > 0; o >>= 1) { s += __shfl_down(s, o); q += __shfl_down(q, o); }
  __shared__ float ss[4], sq[4];
  const int wave = t >> 6, lane = t & 63;
  if (lane == 0) { ss[wave] = s; sq[wave] = q; }
  __syncthreads();
  const float st = ss[0] + ss[1] + ss[2] + ss[3];
  const float qt = sq[0] + sq[1] + sq[2] + sq[3];
  const float mean = st * (1.0f / 1024.0f);
  const float var = qt * (1.0f / 1024.0f) - mean * mean;
  const float inv = rsqrtf(var + 1e-5f);
  u16* o2 = out + row * 1024;
  o2[t]       = f2bf((v0 - mean) * inv * w[t]       + b[t]);
  o2[t + 256] = f2bf((v1 - mean) * inv * w[t + 256] + b[t + 256]);
  o2[t + 512] = f2bf((v2 - mean) * inv * w[t + 512] + b[t + 512]);
  o2[t + 768] = f2bf((v3 - mean) * inv * w[t + 768] + b[t + 768]);
}

// ---------------------------------------------------------------------------
// Causal attention, T=17, hd=64. One block per (batch, head). h += attn output.
// ---------------------------------------------------------------------------
__global__ __launch_bounds__(256) void attn_kernel(const u16* __restrict__ QKV,
                                                   float* __restrict__ h)
{
  const int blk = blockIdx.x;          // 0..8191
  const int b = blk >> 4, head = blk & 15;
  __shared__ float qs[17][64], ks[17][64], vs[17][64];
  __shared__ float sc[17][20];
  const long long base = (long long)b * 17 * 1024 + head * 64;
  const u16* Q  = QKV;
  const u16* Kp = QKV + 8912896LL;       // 8704*1024
  const u16* V  = QKV + 17825792LL;

  for (int i = threadIdx.x; i < 17 * 64; i += 256) {
    const int t = i >> 6, d = i & 63;
    const long long off = base + (long long)t * 1024 + d;
    qs[t][d] = bf2f(Q[off]); ks[t][d] = bf2f(Kp[off]); vs[t][d] = bf2f(V[off]);
  }
  __syncthreads();

  for (int i = threadIdx.x; i < 289; i += 256) {
    const int tq = i / 17, tk = i % 17;
    float a = 0.0f;
    if (tk <= tq) {
#pragma unroll
      for (int d = 0; d < 64; ++d) a += qs[tq][d] * ks[tk][d];
      a *= 0.125f;                     // 1/sqrt(64)
    }
    sc[tq][tk] = a;
  }
  __syncthreads();

  if (threadIdx.x < 17) {
    const int tq = threadIdx.x;
    float m = -1e30f;
    for (int tk = 0; tk <= tq; ++tk) m = fmaxf(m, sc[tq][tk]);
    float s = 0.0f;
    for (int tk = 0; tk <= tq; ++tk) { const float e = __expf(sc[tq][tk] - m); sc[tq][tk] = e; s += e; }
    const float inv = 1.0f / s;
    for (int tk = 0; tk <= tq; ++tk) sc[tq][tk] *= inv;
  }
  __syncthreads();

  for (int i = threadIdx.x; i < 17 * 64; i += 256) {
    const int tq = i >> 6, d = i & 63;
    float a = 0.0f;
    for (int tk = 0; tk <= tq; ++tk) a += sc[tq][tk] * vs[tk][d];
    h[base + (long long)tq * 1024 + d] += a;   // exclusive owner of this slice
  }
}

// ---------------------------------------------------------------------------
// Build patch matrix P bf16 [8704][192]; t=0 thumb = 2x2 avg (bilinear scale-4
// half-pixel), t=1+s patch; cols 147..191 zero-pad (K padded to 192).
// ---------------------------------------------------------------------------
__global__ void build_p(const float* __restrict__ x, u16* __restrict__ P)
{
  const int n = blockIdx.x;
  const int j = threadIdx.x;
  if (j >= 192) return;
  const int b = n / 17, t = n % 17;
  float val = 0.0f;
  if (j < 147) {
    const int c = j / 49, rem = j % 49, p = rem / 7, q = rem % 7;
    const float* xb = x + (long long)(b * 3 + c) * 784;
    if (t == 0) {
      const int r = 4 * p + 1, cc = 4 * q + 1;
      val = 0.25f * (xb[r * 28 + cc] + xb[r * 28 + cc + 1] +
                     xb[(r + 1) * 28 + cc] + xb[(r + 1) * 28 + cc + 1]);
    } else {
      const int s = t - 1, ii = s >> 2, jj = s & 3;
      val = xb[(7 * ii + p) * 28 + 7 * jj + q];
    }
  }
  P[(long long)n * 192 + j] = f2bf(val);
}

// conv_w fp32 [1024][147] -> Wc bf16 [1024][192] (zero-pad K to 192) and
// cw2 bf16 [256][1024]: cw2[j][c] = conv_w[c*147+j], rows 147..255 zero.
__global__ __launch_bounds__(256) void cvt_conv(const float* __restrict__ cw,
                                                u16* __restrict__ Wc, u16* __restrict__ cw2)
{
  const int i = blockIdx.x * 256 + threadIdx.x;     // grid covers 196608 + 262144
  if (i < 196608) {
    const int d = i / 192, j = i % 192;
    Wc[i] = (j < 147) ? f2bf(cw[d * 147 + j]) : (u16)0;
  } else {
    const int i2 = i - 196608;
    if (i2 < 262144) {
      const int j = i2 / 1024, c = i2 % 1024;
      cw2[i2] = (j < 147) ? f2bf(cw[c * 147 + j]) : (u16)0;
    }
  }
}

// Bulk weight convert: 49 x 1M fp32 -> bf16. chunk layout in wAll:
// [l*4 + {0:wq,1:wk,2:wv,3:mlp}] for l=0..11, then [48]=out_w.
__global__ __launch_bounds__(256) void cvt_all(
    const float* __restrict__ wq, const float* __restrict__ wk,
    const float* __restrict__ wv, const float* __restrict__ mlpw,
    const float* __restrict__ outw, u16* __restrict__ wAll)
{
  const int i = blockIdx.x * 256 + threadIdx.x;    // float4 index, < 12,845,056
  const int which = i >> 18;                        // 0..48
  const int off = i & 262143;
  const float4* src;
  if (which < 48) {
    const int layer = which >> 2, sub = which & 3;
    const float* base = (sub == 0) ? wq : (sub == 1) ? wk : (sub == 2) ? wv : mlpw;
    src = (const float4*)(base + (size_t)layer * 1048576) + off;
  } else {
    src = (const float4*)outw + off;
  }
  const float4 v = *src;
  ushort4 o; o.x = f2bf(v.x); o.y = f2bf(v.y); o.z = f2bf(v.z); o.w = f2bf(v.w);
  *(ushort4*)(wAll + (size_t)which * 1048576 + (size_t)off * 4) = o;
}

// per-layer weight cast fallback (small ws): wq,wk,wv -> o3[3][1M], mlp -> om.
__global__ __launch_bounds__(256) void cvt4(const float* __restrict__ a0, const float* __restrict__ a1,
                                            const float* __restrict__ a2, const float* __restrict__ a3,
                                            u16* __restrict__ o3, u16* __restrict__ om)
{
  const int i = blockIdx.x * 256 + threadIdx.x;
  const int which = i >> 20, off = i & 1048575;
  const float* src = (which == 0) ? a0 : (which == 1) ? a1 : (which == 2) ? a2 : a3;
  const float v = src[off];
  if (which < 3) o3[which * 1048576 + off] = f2bf(v);
  else           om[off] = f2bf(v);
}

__global__ __launch_bounds__(256) void cvtN(const float* __restrict__ in, u16* __restrict__ out, int n)
{
  const int i = blockIdx.x * 256 + threadIdx.x;
  if (i < n) out[i] = f2bf(in[i]);
}

// ---------------------------------------------------------------------------
extern "C" void kernel_launch(void* const* d_in, const int* in_sizes, int n_in,
                              void* d_out, int out_size, void* d_ws, size_t ws_size,
                              hipStream_t stream)
{
  const float* x     = (const float*)d_in[0];
  const float* convw = (const float*)d_in[1];
  const float* ln1w  = (const float*)d_in[2];
  const float* ln1b  = (const float*)d_in[3];
  const float* wq    = (const float*)d_in[4];
  const float* wk    = (const float*)d_in[5];
  const float* wv    = (const float*)d_in[6];
  const float* ln2w  = (const float*)d_in[7];
  const float* ln2b  = (const float*)d_in[8];
  const float* mlpw  = (const float*)d_in[9];
  const float* mlpb  = (const float*)d_in[10];
  const float* outw  = (const float*)d_in[11];
  const float* outb  = (const float*)d_in[12];

  char* w = (char*)d_ws;
  const bool big = (ws_size >= 213975040ULL);

  if (big) {
    float* h   = (float*)(w);                   // 35,651,584 B
    u16* Abuf  = (u16*)(w + 35651584);          // 17,825,792 B
    u16* QKV   = (u16*)(w + 53477376);          // 53,477,376 B (also logits bf16)
    u16* wAll  = (u16*)(w + 106954752);         // 102,760,448 B (49 x 1M bf16)
    u16* Wc    = (u16*)(w + 209715200);         //    393,216 B
    u16* cw2   = (u16*)(w + 210108416);         //    524,288 B
    u16* P     = (u16*)(w + 210632704);         //  3,342,336 B -> 213,975,040

    cvt_all<<<50176, 256, 0, stream>>>(wq, wk, wv, mlpw, outw, wAll);
    cvt_conv<<<1792, 256, 0, stream>>>(convw, Wc, cw2);
    build_p<<<8704, 192, 0, stream>>>(x, P);
    gemm_bt<0><<<dim3(8, 68, 1), 256, 0, stream>>>(P, 192, Wc, Wc, Wc, 192, 192,
                                                   (void*)h, 0LL, 1024, nullptr);
    for (int l = 0; l < 12; ++l) {
      u16* wl = wAll + (size_t)l * 4194304;
      ln_kernel<<<8704, 256, 0, stream>>>(h, ln1w + l * 1024, ln1b + l * 1024, Abuf);
      gemm_bt<1><<<dim3(8, 68, 3), 256, 0, stream>>>(Abuf, 1024, wl, wl + 1048576, wl + 2097152,
                                                     1024, 1024, (void*)QKV, 8912896LL, 1024, nullptr);
      attn_kernel<<<8192, 256, 0, stream>>>(QKV, h);
      ln_kernel<<<8704, 256, 0, stream>>>(h, ln2w + l * 1024, ln2b + l * 1024, Abuf);
      gemm_bt<2><<<dim3(8, 68, 1), 256, 0, stream>>>(Abuf, 1024, wl + 3145728, wl, wl,
                                                     1024, 1024, (void*)h, 0LL, 1024, mlpb + l * 1024);
    }
    u16* wout = wAll + (size_t)48 * 1048576;
    cvtN<<<34816, 256, 0, stream>>>(h, Abuf, 8912896);
    gemm_bt<1><<<dim3(8, 68, 1), 256, 0, stream>>>(Abuf, 1024, wout, wout, wout,
                                                   1024, 1024, (void*)QKV, 0LL, 1024, outb);
    gemm_bt<3><<<dim3(2, 68, 1), 256, 0, stream>>>(QKV, 1024, cw2, cw2, cw2,
                                                   1024, 1024, d_out, 0LL, 0, nullptr);
  } else {
    if (ws_size < 119603200ULL) return;
    float* h   = (float*)(w);
    u16* Abuf  = (u16*)(w + 35651584);
    u16* QKV   = (u16*)(w + 53477376);
    u16* wb3   = (u16*)(w + 106954752);          // 6,291,456
    u16* wmb   = (u16*)(w + 113246208);          // 2,097,152
    u16* Wc    = (u16*)(w + 115343360);          //   393,216
    u16* cw2   = (u16*)(w + 115736576);          //   524,288
    u16* P     = (u16*)(w + 116260864);          // 3,342,336 -> 119,603,200

    cvt_conv<<<1792, 256, 0, stream>>>(convw, Wc, cw2);
    build_p<<<8704, 192, 0, stream>>>(x, P);
    gemm_bt<0><<<dim3(8, 68, 1), 256, 0, stream>>>(P, 192, Wc, Wc, Wc, 192, 192,
                                                   (void*)h, 0LL, 1024, nullptr);
    for (int l = 0; l < 12; ++l) {
      const size_t wo = (size_t)l * 1048576;
      cvt4<<<16384, 256, 0, stream>>>(wq + wo, wk + wo, wv + wo, mlpw + wo, wb3, wmb);
      ln_kernel<<<8704, 256, 0, stream>>>(h, ln1w + l * 1024, ln1b + l * 1024, Abuf);
      gemm_bt<1><<<dim3(8, 68, 3), 256, 0, stream>>>(Abuf, 1024, wb3, wb3 + 1048576, wb3 + 2097152,
                                                     1024, 1024, (void*)QKV, 8912896LL, 1024, nullptr);
      attn_kernel<<<8192, 256, 0, stream>>>(QKV, h);
      ln_kernel<<<8704, 256, 0, stream>>>(h, ln2w + l * 1024, ln2b + l * 1024, Abuf);
      gemm_bt<2><<<dim3(8, 68, 1), 256, 0, stream>>>(Abuf, 1024, wmb, wmb, wmb,
                                                     1024, 1024, (void*)h, 0LL, 1024, mlpb + l * 1024);
    }
    cvtN<<<34816, 256, 0, stream>>>(h, Abuf, 8912896);
    cvtN<<<4096, 256, 0, stream>>>(outw, wmb, 1048576);
    gemm_bt<1><<<dim3(8, 68, 1), 256, 0, stream>>>(Abuf, 1024, wmb, wmb, wmb,
                                                   1024, 1024, (void*)QKV, 0LL, 1024, outb);
    gemm_bt<3><<<dim3(2, 68, 1), 256, 0, stream>>>(QKV, 1024, cw2, cw2, cw2,
                                                   1024, 1024, d_out, 0LL, 0, nullptr);
  }
}

// Round 6
// 2957.235 us; speedup vs baseline: 1.7380x; 1.7380x over previous
//
#include <hip/hip_runtime.h>

// Net_87814901334404: B=512, CI=3, HW=28, K=7, C=1024, NH=16, L=12, T=17, M=B*T=8704
// Round 6 = Round 5 with two bug fixes:
//  (1) MODE4 shadow now written to QKV (was Abuf = the GEMM's OWN A input -> WAR race).
//  (2) attn PV stage is a strided loop (was `if(tid<272)` with 256 threads ->
//      row tq=16 dropped every layer).
// GEMM core remains byte-identical to R3 (best measured: 94us QKV).

typedef unsigned short u16;
typedef short bfrag8 __attribute__((ext_vector_type(8)));
typedef float facc4 __attribute__((ext_vector_type(4)));

__device__ __forceinline__ u16 f2bf(float f) {
  union { float f; unsigned u; } x; x.f = f;
  unsigned r = x.u + 0x7fffu + ((x.u >> 16) & 1u);   // round-to-nearest-even
  return (u16)(r >> 16);
}
__device__ __forceinline__ float bf2f(u16 h) {
  union { unsigned u; float f; } x; x.u = ((unsigned)h) << 16;
  return x.f;
}

// ---------------------------------------------------------------------------
// GEMM: out[m,n] = sum_k A[m,k]*B[n,k]  (B row-major [N][K], out = A @ B^T)
// bf16 in, fp32 acc, mfma_f32_16x16x32_bf16 (A/B frag: idx=lane&15, k=quad*8+j;
// C/D: col=lane&15, row=quad*4+reg — learn_hip m89/m91).
// BK=64 staged as two BK=32 sub-tiles (R3 structure, measured 94us on QKV).
// MODE 0: f32 out=acc(+bias); 1: bf16 out=acc(+bias); 2: f32 out+=acc(+bias);
// 3: f32 deconv scatter (+bias); 4: f32 out+=acc(+bias) AND bf16 shadow at
// (u16*)zstride (shadow must NOT alias A/B!). blockIdx: x=N-tile, y=M-tile,
// z picks B0/B1/B2 + z*zstride out offset (QKV batching).
// ---------------------------------------------------------------------------
template <int MODE>
__global__ __launch_bounds__(256) void gemm_bt(
    const u16* __restrict__ A, int lda,
    const u16* __restrict__ B0, const u16* __restrict__ B1, const u16* __restrict__ B2,
    int ldb, int K,
    void* __restrict__ outp, long long zstride, int ldo,
    const float* __restrict__ bias)
{
  __shared__ __align__(16) u16 As[8192];   // 16KB: [t][128][32]
  __shared__ __align__(16) u16 Bs[8192];   // 16KB

  const int n0 = blockIdx.x * 128;
  const int m0 = blockIdx.y * 128;
  const int z  = blockIdx.z;
  const u16* __restrict__ B = (z == 0) ? B0 : ((z == 1) ? B1 : B2);

  const int tid  = threadIdx.x;
  const int wave = tid >> 6;
  const int lane = tid & 63;
  const int wm   = (wave >> 1) * 64;
  const int wn   = (wave & 1) * 64;
  const int lrow = lane & 15;
  const int lquad = lane >> 4;

  facc4 acc[4][4] = {};

  // staging pointers: slot s_j = tid + 256*j, j=0..3 (per matrix)
  const u16* ga[4]; const u16* gb[4];
#pragma unroll
  for (int j = 0; j < 4; ++j) {
    const int s = tid + 256 * j;
    const int t = s >> 9, s2 = s & 511;
    const int r = s2 >> 2, c = (s2 & 3) + 4 * t;
    ga[j] = A + (long long)(m0 + r) * lda + c * 8;
    gb[j] = B + (long long)(n0 + r) * ldb + c * 8;
  }

  // frag LDS element offsets (loop-invariant)
  const int aoff = (wm + lrow) * 32 + lquad * 8;
  const int boff = (wn + lrow) * 32 + lquad * 8;

  for (int k0 = 0; k0 < K; k0 += 64) {
#pragma unroll
    for (int j = 0; j < 4; ++j) {
      __builtin_amdgcn_global_load_lds((const __attribute__((address_space(1))) void*)ga[j],
                                       (__attribute__((address_space(3))) void*)(As + (tid + 256 * j) * 8), 16, 0, 0);
      __builtin_amdgcn_global_load_lds((const __attribute__((address_space(1))) void*)gb[j],
                                       (__attribute__((address_space(3))) void*)(Bs + (tid + 256 * j) * 8), 16, 0, 0);
      ga[j] += 64; gb[j] += 64;
    }
    __syncthreads();   // drains vmcnt -> both k-halves resident

#pragma unroll
    for (int t = 0; t < 2; ++t) {
      bfrag8 af[4], bfr[4];
#pragma unroll
      for (int im = 0; im < 4; ++im) af[im] = *(const bfrag8*)(As + t * 4096 + aoff + 512 * im);
#pragma unroll
      for (int in = 0; in < 4; ++in) bfr[in] = *(const bfrag8*)(Bs + t * 4096 + boff + 512 * in);
#pragma unroll
      for (int im = 0; im < 4; ++im)
#pragma unroll
        for (int in = 0; in < 4; ++in)
          acc[im][in] = __builtin_amdgcn_mfma_f32_16x16x32_bf16(af[im], bfr[in], acc[im][in], 0, 0, 0);
    }
    __syncthreads();   // before next iteration overwrites LDS
  }

#pragma unroll
  for (int in = 0; in < 4; ++in) {
    const int col = n0 + wn + in * 16 + lrow;
    const float bb = bias ? bias[col] : 0.0f;
#pragma unroll
    for (int im = 0; im < 4; ++im) {
#pragma unroll
      for (int r = 0; r < 4; ++r) {
        const int row = m0 + wm + im * 16 + lquad * 4 + r;
        const float v = acc[im][in][r] + bb;
        if (MODE == 0) {
          ((float*)outp)[(long long)row * ldo + col] = v;
        } else if (MODE == 1) {
          (((u16*)outp) + zstride * z)[(long long)row * ldo + col] = f2bf(v);
        } else if (MODE == 2) {
          ((float*)outp)[(long long)row * ldo + col] += v;
        } else if (MODE == 4) {
          const long long off = (long long)row * ldo + col;
          const float nv = ((float*)outp)[off] + v;
          ((float*)outp)[off] = nv;
          ((u16*)zstride)[off] = f2bf(nv);   // shadow buffer: no alias with A/B
        } else {  // MODE 3: deconv scatter. row=b*17+s, col=d*49+hk*7+wk (<147)
          if (col < 147) {
            const int b = row / 17, s = row - b * 17;
            const int d = col / 49, rem = col - d * 49;
            const int hk = rem / 7, wk = rem - hk * 7;
            ((float*)outp)[(long long)((b * 3 + d) * 7 + hk) * 119 + s * 7 + wk] = v;
          }
        }
      }
    }
  }
}

// ---------------------------------------------------------------------------
// LayerNorm over C=1024: fp32 h row -> bf16 normalized row. float4/ushort4.
// ---------------------------------------------------------------------------
__global__ __launch_bounds__(256) void ln_kernel(
    const float* __restrict__ h, const float* __restrict__ w,
    const float* __restrict__ b, u16* __restrict__ out)
{
  const long long row = blockIdx.x;
  const int t = threadIdx.x;
  const float4 v = ((const float4*)(h + row * 1024))[t];
  float s = v.x + v.y + v.z + v.w;
  float q = v.x * v.x + v.y * v.y + v.z * v.z + v.w * v.w;
  for (int o = 32; o > 0; o >>= 1) { s += __shfl_down(s, o); q += __shfl_down(q, o); }
  __shared__ float ss[4], sq[4];
  const int wave = t >> 6, lane = t & 63;
  if (lane == 0) { ss[wave] = s; sq[wave] = q; }
  __syncthreads();
  const float st = ss[0] + ss[1] + ss[2] + ss[3];
  const float qt = sq[0] + sq[1] + sq[2] + sq[3];
  const float mean = st * (1.0f / 1024.0f);
  const float var = qt * (1.0f / 1024.0f) - mean * mean;
  const float inv = rsqrtf(var + 1e-5f);
  const float4 w4 = ((const float4*)w)[t];
  const float4 b4 = ((const float4*)b)[t];
  ushort4 o;
  o.x = f2bf((v.x - mean) * inv * w4.x + b4.x);
  o.y = f2bf((v.y - mean) * inv * w4.y + b4.y);
  o.z = f2bf((v.z - mean) * inv * w4.z + b4.z);
  o.w = f2bf((v.w - mean) * inv * w4.w + b4.w);
  ((ushort4*)(out + row * 1024))[t] = o;
}

// ---------------------------------------------------------------------------
// Causal attention, T=17, hd=64. One block per (batch, head). h += attn out.
// uint4 QKV loads, float4 h read-modify-write. PV stage loops (272 items).
// ---------------------------------------------------------------------------
__global__ __launch_bounds__(256) void attn_kernel(const u16* __restrict__ QKV,
                                                   float* __restrict__ h)
{
  const int blk = blockIdx.x;          // 0..8191
  const int b = blk >> 4, head = blk & 15;
  __shared__ float qs[17][64], ks[17][64], vs[17][64];
  __shared__ float sc[17][20];
  const long long base = (long long)b * 17408 + head * 64;   // 17*1024
  const u16* Q  = QKV;
  const u16* Kp = QKV + 8912896LL;       // 8704*1024
  const u16* V  = QKV + 17825792LL;
  const int tid = threadIdx.x;

  if (tid < 136) {                        // 17 rows x 8 chunks of 8 bf16
    const int t = tid >> 3, dg = (tid & 7) * 8;
    const long long off = base + (long long)t * 1024 + dg;
    union { uint4 u; u16 s[8]; } xq, xk, xv;
    xq.u = *(const uint4*)(Q + off);
    xk.u = *(const uint4*)(Kp + off);
    xv.u = *(const uint4*)(V + off);
#pragma unroll
    for (int j = 0; j < 8; ++j) {
      qs[t][dg + j] = bf2f(xq.s[j]);
      ks[t][dg + j] = bf2f(xk.s[j]);
      vs[t][dg + j] = bf2f(xv.s[j]);
    }
  }
  __syncthreads();

  for (int i = tid; i < 289; i += 256) {
    const int tq = i / 17, tk = i % 17;
    float a = 0.0f;
    if (tk <= tq) {
#pragma unroll
      for (int d = 0; d < 64; ++d) a += qs[tq][d] * ks[tk][d];
      a *= 0.125f;                     // 1/sqrt(64)
    }
    sc[tq][tk] = a;
  }
  __syncthreads();

  if (tid < 17) {
    const int tq = tid;
    float m = -1e30f;
    for (int tk = 0; tk <= tq; ++tk) m = fmaxf(m, sc[tq][tk]);
    float s = 0.0f;
    for (int tk = 0; tk <= tq; ++tk) { const float e = __expf(sc[tq][tk] - m); sc[tq][tk] = e; s += e; }
    const float inv = 1.0f / s;
    for (int tk = 0; tk <= tq; ++tk) sc[tq][tk] *= inv;
  }
  __syncthreads();

  for (int i = tid; i < 272; i += 256) {  // 17 rows x 16 float4 groups (loop!)
    const int tq = i >> 4, dg = (i & 15) * 4;
    float o0 = 0, o1 = 0, o2 = 0, o3 = 0;
    for (int tk = 0; tk <= tq; ++tk) {
      const float s = sc[tq][tk];
      o0 += s * vs[tk][dg];     o1 += s * vs[tk][dg + 1];
      o2 += s * vs[tk][dg + 2]; o3 += s * vs[tk][dg + 3];
    }
    float4* hp = (float4*)(h + base + (long long)tq * 1024 + dg);
    float4 hv = *hp;
    hv.x += o0; hv.y += o1; hv.z += o2; hv.w += o3;
    *hp = hv;                             // exclusive owner of this slice
  }
}

// ---------------------------------------------------------------------------
// Build patch matrix P bf16 [8704][192]; t=0 thumb = 2x2 avg (bilinear scale-4
// half-pixel), t=1+s patch; cols 147..191 zero-pad (K padded to 192).
// ---------------------------------------------------------------------------
__global__ void build_p(const float* __restrict__ x, u16* __restrict__ P)
{
  const int n = blockIdx.x;
  const int j = threadIdx.x;
  if (j >= 192) return;
  const int b = n / 17, t = n % 17;
  float val = 0.0f;
  if (j < 147) {
    const int c = j / 49, rem = j % 49, p = rem / 7, q = rem % 7;
    const float* xb = x + (long long)(b * 3 + c) * 784;
    if (t == 0) {
      const int r = 4 * p + 1, cc = 4 * q + 1;
      val = 0.25f * (xb[r * 28 + cc] + xb[r * 28 + cc + 1] +
                     xb[(r + 1) * 28 + cc] + xb[(r + 1) * 28 + cc + 1]);
    } else {
      const int s = t - 1, ii = s >> 2, jj = s & 3;
      val = xb[(7 * ii + p) * 28 + 7 * jj + q];
    }
  }
  P[(long long)n * 192 + j] = f2bf(val);
}

// conv_w fp32 [1024][147] -> Wc bf16 [1024][192] (zero-pad K to 192) and
// cw2 bf16 [256][1024]: cw2[j][c] = conv_w[c*147+j], rows 147..255 zero.
__global__ __launch_bounds__(256) void cvt_conv(const float* __restrict__ cw,
                                                u16* __restrict__ Wc, u16* __restrict__ cw2)
{
  const int i = blockIdx.x * 256 + threadIdx.x;     // grid covers 196608 + 262144
  if (i < 196608) {
    const int d = i / 192, j = i % 192;
    Wc[i] = (j < 147) ? f2bf(cw[d * 147 + j]) : (u16)0;
  } else {
    const int i2 = i - 196608;
    if (i2 < 262144) {
      const int j = i2 / 1024, c = i2 % 1024;
      cw2[i2] = (j < 147) ? f2bf(cw[c * 147 + j]) : (u16)0;
    }
  }
}

// W'[j][k] = sum_c cw2[j][c] * outw[c][k]  (fused out-proj+deconv weight).
// grid (4, 256): x=k-group, y=j. Coalesced outw reads across lanes.
__global__ __launch_bounds__(256) void wprime_kernel(
    const u16* __restrict__ cw2, const float* __restrict__ outw,
    u16* __restrict__ Wp)
{
  const int k = blockIdx.x * 256 + threadIdx.x;
  const int j = blockIdx.y;
  float a = 0.0f;
  for (int c = 0; c < 1024; ++c)
    a += bf2f(cw2[j * 1024 + c]) * outw[c * 1024 + k];
  Wp[j * 1024 + k] = f2bf(a);
}

// b'[j] = sum_c outb[c] * cw2[j][c]. One block, 256 threads.
__global__ __launch_bounds__(256) void bprime_kernel(
    const u16* __restrict__ cw2, const float* __restrict__ outb,
    float* __restrict__ bp)
{
  const int j = threadIdx.x;
  float a = 0.0f;
  for (int c = 0; c < 1024; ++c) a += outb[c] * bf2f(cw2[j * 1024 + c]);
  bp[j] = a;
}

// Bulk weight convert: 49 x 1M fp32 -> bf16. chunk layout in wAll:
// [l*4 + {0:wq,1:wk,2:wv,3:mlp}] for l=0..11, then [48]=out_w (unused in big).
__global__ __launch_bounds__(256) void cvt_all(
    const float* __restrict__ wq, const float* __restrict__ wk,
    const float* __restrict__ wv, const float* __restrict__ mlpw,
    const float* __restrict__ outw, u16* __restrict__ wAll)
{
  const int i = blockIdx.x * 256 + threadIdx.x;    // float4 index, < 12,845,056
  const int which = i >> 18;                        // 0..48
  const int off = i & 262143;
  const float4* src;
  if (which < 48) {
    const int layer = which >> 2, sub = which & 3;
    const float* base = (sub == 0) ? wq : (sub == 1) ? wk : (sub == 2) ? wv : mlpw;
    src = (const float4*)(base + (size_t)layer * 1048576) + off;
  } else {
    src = (const float4*)outw + off;
  }
  const float4 v = *src;
  ushort4 o; o.x = f2bf(v.x); o.y = f2bf(v.y); o.z = f2bf(v.z); o.w = f2bf(v.w);
  *(ushort4*)(wAll + (size_t)which * 1048576 + (size_t)off * 4) = o;
}

// per-layer weight cast fallback (small ws): wq,wk,wv -> o3[3][1M], mlp -> om.
__global__ __launch_bounds__(256) void cvt4(const float* __restrict__ a0, const float* __restrict__ a1,
                                            const float* __restrict__ a2, const float* __restrict__ a3,
                                            u16* __restrict__ o3, u16* __restrict__ om)
{
  const int i = blockIdx.x * 256 + threadIdx.x;
  const int which = i >> 20, off = i & 1048575;
  const float* src = (which == 0) ? a0 : (which == 1) ? a1 : (which == 2) ? a2 : a3;
  const float v = src[off];
  if (which < 3) o3[which * 1048576 + off] = f2bf(v);
  else           om[off] = f2bf(v);
}

__global__ __launch_bounds__(256) void cvtN(const float* __restrict__ in, u16* __restrict__ out, int n)
{
  const int i = blockIdx.x * 256 + threadIdx.x;
  if (i < n) out[i] = f2bf(in[i]);
}

// ---------------------------------------------------------------------------
extern "C" void kernel_launch(void* const* d_in, const int* in_sizes, int n_in,
                              void* d_out, int out_size, void* d_ws, size_t ws_size,
                              hipStream_t stream)
{
  const float* x     = (const float*)d_in[0];
  const float* convw = (const float*)d_in[1];
  const float* ln1w  = (const float*)d_in[2];
  const float* ln1b  = (const float*)d_in[3];
  const float* wq    = (const float*)d_in[4];
  const float* wk    = (const float*)d_in[5];
  const float* wv    = (const float*)d_in[6];
  const float* ln2w  = (const float*)d_in[7];
  const float* ln2b  = (const float*)d_in[8];
  const float* mlpw  = (const float*)d_in[9];
  const float* mlpb  = (const float*)d_in[10];
  const float* outw  = (const float*)d_in[11];
  const float* outb  = (const float*)d_in[12];

  char* w = (char*)d_ws;
  const bool big = (ws_size >= 214500352ULL);

  if (big) {
    float* h   = (float*)(w);                   // 35,651,584 B
    u16* Abuf  = (u16*)(w + 35651584);          // 17,825,792 B
    u16* QKV   = (u16*)(w + 53477376);          // 53,477,376 B (dead after last attn
                                                //   -> reused as bf16 h-shadow)
    u16* wAll  = (u16*)(w + 106954752);         // 102,760,448 B (49 x 1M bf16)
    u16* Wc    = (u16*)(w + 209715200);         //    393,216 B
    u16* cw2   = (u16*)(w + 210108416);         //    524,288 B
    u16* P     = (u16*)(w + 210632704);         //  3,342,336 B
    u16* Wp    = (u16*)(w + 213975040);         //    524,288 B
    float* bp  = (float*)(w + 214499328);       //      1,024 B -> 214,500,352

    cvt_all<<<50176, 256, 0, stream>>>(wq, wk, wv, mlpw, outw, wAll);
    cvt_conv<<<1792, 256, 0, stream>>>(convw, Wc, cw2);
    wprime_kernel<<<dim3(4, 256), 256, 0, stream>>>(cw2, outw, Wp);
    bprime_kernel<<<1, 256, 0, stream>>>(cw2, outb, bp);
    build_p<<<8704, 192, 0, stream>>>(x, P);
    gemm_bt<0><<<dim3(8, 68, 1), 256, 0, stream>>>(P, 192, Wc, Wc, Wc, 192, 192,
                                                   (void*)h, 0LL, 1024, nullptr);
    for (int l = 0; l < 12; ++l) {
      u16* wl = wAll + (size_t)l * 4194304;
      ln_kernel<<<8704, 256, 0, stream>>>(h, ln1w + l * 1024, ln1b + l * 1024, Abuf);
      gemm_bt<1><<<dim3(8, 68, 3), 256, 0, stream>>>(Abuf, 1024, wl, wl + 1048576, wl + 2097152,
                                                     1024, 1024, (void*)QKV, 8912896LL, 1024, nullptr);
      attn_kernel<<<8192, 256, 0, stream>>>(QKV, h);
      ln_kernel<<<8704, 256, 0, stream>>>(h, ln2w + l * 1024, ln2b + l * 1024, Abuf);
      if (l < 11) {
        gemm_bt<2><<<dim3(8, 68, 1), 256, 0, stream>>>(Abuf, 1024, wl + 3145728, wl, wl,
                                                       1024, 1024, (void*)h, 0LL, 1024, mlpb + l * 1024);
      } else {  // last MLP: h += v AND bf16 shadow into QKV (dead; NOT an input)
        gemm_bt<4><<<dim3(8, 68, 1), 256, 0, stream>>>(Abuf, 1024, wl + 3145728, wl, wl,
                                                       1024, 1024, (void*)h,
                                                       (long long)(uintptr_t)QKV, 1024,
                                                       mlpb + l * 1024);
      }
    }
    // fused out-proj+decode: d_out = scatter(h_bf16 @ W'^T + b')
    gemm_bt<3><<<dim3(2, 68, 1), 256, 0, stream>>>(QKV, 1024, Wp, Wp, Wp,
                                                   1024, 1024, d_out, 0LL, 0, bp);
  } else {
    if (ws_size < 119603200ULL) return;
    float* h   = (float*)(w);
    u16* Abuf  = (u16*)(w + 35651584);
    u16* QKV   = (u16*)(w + 53477376);
    u16* wb3   = (u16*)(w + 106954752);          // 6,291,456
    u16* wmb   = (u16*)(w + 113246208);          // 2,097,152
    u16* Wc    = (u16*)(w + 115343360);          //   393,216
    u16* cw2   = (u16*)(w + 115736576);          //   524,288
    u16* P     = (u16*)(w + 116260864);          // 3,342,336 -> 119,603,200

    cvt_conv<<<1792, 256, 0, stream>>>(convw, Wc, cw2);
    build_p<<<8704, 192, 0, stream>>>(x, P);
    gemm_bt<0><<<dim3(8, 68, 1), 256, 0, stream>>>(P, 192, Wc, Wc, Wc, 192, 192,
                                                   (void*)h, 0LL, 1024, nullptr);
    for (int l = 0; l < 12; ++l) {
      const size_t wo = (size_t)l * 1048576;
      cvt4<<<16384, 256, 0, stream>>>(wq + wo, wk + wo, wv + wo, mlpw + wo, wb3, wmb);
      ln_kernel<<<8704, 256, 0, stream>>>(h, ln1w + l * 1024, ln1b + l * 1024, Abuf);
      gemm_bt<1><<<dim3(8, 68, 3), 256, 0, stream>>>(Abuf, 1024, wb3, wb3 + 1048576, wb3 + 2097152,
                                                     1024, 1024, (void*)QKV, 8912896LL, 1024, nullptr);
      attn_kernel<<<8192, 256, 0, stream>>>(QKV, h);
      ln_kernel<<<8704, 256, 0, stream>>>(h, ln2w + l * 1024, ln2b + l * 1024, Abuf);
      gemm_bt<2><<<dim3(8, 68, 1), 256, 0, stream>>>(Abuf, 1024, wmb, wmb, wmb,
                                                     1024, 1024, (void*)h, 0LL, 1024, mlpb + l * 1024);
    }
    cvtN<<<34816, 256, 0, stream>>>(h, Abuf, 8912896);
    cvtN<<<4096, 256, 0, stream>>>(outw, wmb, 1048576);
    gemm_bt<1><<<dim3(8, 68, 1), 256, 0, stream>>>(Abuf, 1024, wmb, wmb, wmb,
                                                   1024, 1024, (void*)QKV, 0LL, 1024, outb);
    gemm_bt<3><<<dim3(2, 68, 1), 256, 0, stream>>>(QKV, 1024, cw2, cw2, cw2,
                                                   1024, 1024, d_out, 0LL, 0, nullptr);
  }
}

// Round 7
// 2775.460 us; speedup vs baseline: 1.8518x; 1.0655x over previous
//
#include <hip/hip_runtime.h>

// Net_87814901334404: B=512, CI=3, HW=28, K=7, C=1024, NH=16, L=12, T=17, M=B*T=8704
// Round 7 = Round 6 + XCD-aware 1D grid swizzle for gemm_bt.
// Counters showed QKV GEMM moves 252MB L2-fill per dispatch (A panels refetched
// by all 8 XCDs). New mapping: block l -> xcd=l&7, slot=l>>3; per XCD: z-epoch
// outer, M-stripe y=xcd+8*g, x inner => per-XCD working set ~ A-stripe 2.2MB +
// one 2MB weight = L2-resident. GEMM inner loop / epilogues unchanged from R6.

typedef unsigned short u16;
typedef short bfrag8 __attribute__((ext_vector_type(8)));
typedef float facc4 __attribute__((ext_vector_type(4)));

__device__ __forceinline__ u16 f2bf(float f) {
  union { float f; unsigned u; } x; x.f = f;
  unsigned r = x.u + 0x7fffu + ((x.u >> 16) & 1u);   // round-to-nearest-even
  return (u16)(r >> 16);
}
__device__ __forceinline__ float bf2f(u16 h) {
  union { unsigned u; float f; } x; x.u = ((unsigned)h) << 16;
  return x.f;
}

// ---------------------------------------------------------------------------
// GEMM: out[m,n] = sum_k A[m,k]*B[n,k]  (B row-major [N][K], out = A @ B^T)
// bf16 in, fp32 acc, mfma_f32_16x16x32_bf16 (A/B frag: idx=lane&15, k=quad*8+j;
// C/D: col=lane&15, row=quad*4+reg — learn_hip m89/m91).
// BK=64 staged as two BK=32 sub-tiles (R3 structure).
// 1D grid, XCD swizzle: l -> xcd=l&7, j=l>>3; epoch z=j/(9*NX);
// y = xcd + 8*((j%(9*NX))/NX)  (M-tiles, 68 valid, y>=68 dead-exit);
// x = j%NX (N-tile). Grid size must be 8*NZ*9*NX.
// MODE 0: f32 out=acc(+bias); 1: bf16 out=acc(+bias); 2: f32 out+=acc(+bias);
// 3: f32 deconv scatter (+bias); 4: f32 out+=acc(+bias) AND bf16 shadow at
// (u16*)zstride (shadow must NOT alias A/B!).
// ---------------------------------------------------------------------------
template <int MODE>
__global__ __launch_bounds__(256) void gemm_bt(
    const u16* __restrict__ A, int lda,
    const u16* __restrict__ B0, const u16* __restrict__ B1, const u16* __restrict__ B2,
    int ldb, int K, int NX,
    void* __restrict__ outp, long long zstride, int ldo,
    const float* __restrict__ bias)
{
  __shared__ __align__(16) u16 As[8192];   // 16KB: [t][128][32]
  __shared__ __align__(16) u16 Bs[8192];   // 16KB

  const int l = blockIdx.x;
  const int xcd = l & 7;
  const int j = l >> 3;
  const int per_epoch = 9 * NX;
  const int z = j / per_epoch;
  const int r2 = j - z * per_epoch;
  const int g = r2 / NX;
  const int y = xcd + 8 * g;
  if (y >= 68) return;                      // dead block (uniform) — exits before barriers
  const int x = r2 - g * NX;
  const int n0 = x * 128;
  const int m0 = y * 128;
  const u16* __restrict__ B = (z == 0) ? B0 : ((z == 1) ? B1 : B2);

  const int tid  = threadIdx.x;
  const int wave = tid >> 6;
  const int lane = tid & 63;
  const int wm   = (wave >> 1) * 64;
  const int wn   = (wave & 1) * 64;
  const int lrow = lane & 15;
  const int lquad = lane >> 4;

  facc4 acc[4][4] = {};

  // staging pointers: slot s_j = tid + 256*j2, j2=0..3 (per matrix)
  const u16* ga[4]; const u16* gb[4];
#pragma unroll
  for (int j2 = 0; j2 < 4; ++j2) {
    const int s = tid + 256 * j2;
    const int t = s >> 9, s2 = s & 511;
    const int r = s2 >> 2, c = (s2 & 3) + 4 * t;
    ga[j2] = A + (long long)(m0 + r) * lda + c * 8;
    gb[j2] = B + (long long)(n0 + r) * ldb + c * 8;
  }

  // frag LDS element offsets (loop-invariant)
  const int aoff = (wm + lrow) * 32 + lquad * 8;
  const int boff = (wn + lrow) * 32 + lquad * 8;

  for (int k0 = 0; k0 < K; k0 += 64) {
#pragma unroll
    for (int j2 = 0; j2 < 4; ++j2) {
      __builtin_amdgcn_global_load_lds((const __attribute__((address_space(1))) void*)ga[j2],
                                       (__attribute__((address_space(3))) void*)(As + (tid + 256 * j2) * 8), 16, 0, 0);
      __builtin_amdgcn_global_load_lds((const __attribute__((address_space(1))) void*)gb[j2],
                                       (__attribute__((address_space(3))) void*)(Bs + (tid + 256 * j2) * 8), 16, 0, 0);
      ga[j2] += 64; gb[j2] += 64;
    }
    __syncthreads();   // drains vmcnt -> both k-halves resident

#pragma unroll
    for (int t = 0; t < 2; ++t) {
      bfrag8 af[4], bfr[4];
#pragma unroll
      for (int im = 0; im < 4; ++im) af[im] = *(const bfrag8*)(As + t * 4096 + aoff + 512 * im);
#pragma unroll
      for (int in = 0; in < 4; ++in) bfr[in] = *(const bfrag8*)(Bs + t * 4096 + boff + 512 * in);
#pragma unroll
      for (int im = 0; im < 4; ++im)
#pragma unroll
        for (int in = 0; in < 4; ++in)
          acc[im][in] = __builtin_amdgcn_mfma_f32_16x16x32_bf16(af[im], bfr[in], acc[im][in], 0, 0, 0);
    }
    __syncthreads();   // before next iteration overwrites LDS
  }

#pragma unroll
  for (int in = 0; in < 4; ++in) {
    const int col = n0 + wn + in * 16 + lrow;
    const float bb = bias ? bias[col] : 0.0f;
#pragma unroll
    for (int im = 0; im < 4; ++im) {
#pragma unroll
      for (int r = 0; r < 4; ++r) {
        const int row = m0 + wm + im * 16 + lquad * 4 + r;
        const float v = acc[im][in][r] + bb;
        if (MODE == 0) {
          ((float*)outp)[(long long)row * ldo + col] = v;
        } else if (MODE == 1) {
          (((u16*)outp) + zstride * z)[(long long)row * ldo + col] = f2bf(v);
        } else if (MODE == 2) {
          ((float*)outp)[(long long)row * ldo + col] += v;
        } else if (MODE == 4) {
          const long long off = (long long)row * ldo + col;
          const float nv = ((float*)outp)[off] + v;
          ((float*)outp)[off] = nv;
          ((u16*)zstride)[off] = f2bf(nv);   // shadow buffer: no alias with A/B
        } else {  // MODE 3: deconv scatter. row=b*17+s, col=d*49+hk*7+wk (<147)
          if (col < 147) {
            const int b = row / 17, s = row - b * 17;
            const int d = col / 49, rem = col - d * 49;
            const int hk = rem / 7, wk = rem - hk * 7;
            ((float*)outp)[(long long)((b * 3 + d) * 7 + hk) * 119 + s * 7 + wk] = v;
          }
        }
      }
    }
  }
}

// ---------------------------------------------------------------------------
// LayerNorm over C=1024: fp32 h row -> bf16 normalized row. float4/ushort4.
// ---------------------------------------------------------------------------
__global__ __launch_bounds__(256) void ln_kernel(
    const float* __restrict__ h, const float* __restrict__ w,
    const float* __restrict__ b, u16* __restrict__ out)
{
  const long long row = blockIdx.x;
  const int t = threadIdx.x;
  const float4 v = ((const float4*)(h + row * 1024))[t];
  float s = v.x + v.y + v.z + v.w;
  float q = v.x * v.x + v.y * v.y + v.z * v.z + v.w * v.w;
  for (int o = 32; o > 0; o >>= 1) { s += __shfl_down(s, o); q += __shfl_down(q, o); }
  __shared__ float ss[4], sq[4];
  const int wave = t >> 6, lane = t & 63;
  if (lane == 0) { ss[wave] = s; sq[wave] = q; }
  __syncthreads();
  const float st = ss[0] + ss[1] + ss[2] + ss[3];
  const float qt = sq[0] + sq[1] + sq[2] + sq[3];
  const float mean = st * (1.0f / 1024.0f);
  const float var = qt * (1.0f / 1024.0f) - mean * mean;
  const float inv = rsqrtf(var + 1e-5f);
  const float4 w4 = ((const float4*)w)[t];
  const float4 b4 = ((const float4*)b)[t];
  ushort4 o;
  o.x = f2bf((v.x - mean) * inv * w4.x + b4.x);
  o.y = f2bf((v.y - mean) * inv * w4.y + b4.y);
  o.z = f2bf((v.z - mean) * inv * w4.z + b4.z);
  o.w = f2bf((v.w - mean) * inv * w4.w + b4.w);
  ((ushort4*)(out + row * 1024))[t] = o;
}

// ---------------------------------------------------------------------------
// Causal attention, T=17, hd=64. One block per (batch, head). h += attn out.
// uint4 QKV loads, float4 h read-modify-write. PV stage loops (272 items).
// ---------------------------------------------------------------------------
__global__ __launch_bounds__(256) void attn_kernel(const u16* __restrict__ QKV,
                                                   float* __restrict__ h)
{
  const int blk = blockIdx.x;          // 0..8191
  const int b = blk >> 4, head = blk & 15;
  __shared__ float qs[17][64], ks[17][64], vs[17][64];
  __shared__ float sc[17][20];
  const long long base = (long long)b * 17408 + head * 64;   // 17*1024
  const u16* Q  = QKV;
  const u16* Kp = QKV + 8912896LL;       // 8704*1024
  const u16* V  = QKV + 17825792LL;
  const int tid = threadIdx.x;

  if (tid < 136) {                        // 17 rows x 8 chunks of 8 bf16
    const int t = tid >> 3, dg = (tid & 7) * 8;
    const long long off = base + (long long)t * 1024 + dg;
    union { uint4 u; u16 s[8]; } xq, xk, xv;
    xq.u = *(const uint4*)(Q + off);
    xk.u = *(const uint4*)(Kp + off);
    xv.u = *(const uint4*)(V + off);
#pragma unroll
    for (int j = 0; j < 8; ++j) {
      qs[t][dg + j] = bf2f(xq.s[j]);
      ks[t][dg + j] = bf2f(xk.s[j]);
      vs[t][dg + j] = bf2f(xv.s[j]);
    }
  }
  __syncthreads();

  for (int i = tid; i < 289; i += 256) {
    const int tq = i / 17, tk = i % 17;
    float a = 0.0f;
    if (tk <= tq) {
#pragma unroll
      for (int d = 0; d < 64; ++d) a += qs[tq][d] * ks[tk][d];
      a *= 0.125f;                     // 1/sqrt(64)
    }
    sc[tq][tk] = a;
  }
  __syncthreads();

  if (tid < 17) {
    const int tq = tid;
    float m = -1e30f;
    for (int tk = 0; tk <= tq; ++tk) m = fmaxf(m, sc[tq][tk]);
    float s = 0.0f;
    for (int tk = 0; tk <= tq; ++tk) { const float e = __expf(sc[tq][tk] - m); sc[tq][tk] = e; s += e; }
    const float inv = 1.0f / s;
    for (int tk = 0; tk <= tq; ++tk) sc[tq][tk] *= inv;
  }
  __syncthreads();

  for (int i = tid; i < 272; i += 256) {  // 17 rows x 16 float4 groups (loop!)
    const int tq = i >> 4, dg = (i & 15) * 4;
    float o0 = 0, o1 = 0, o2 = 0, o3 = 0;
    for (int tk = 0; tk <= tq; ++tk) {
      const float s = sc[tq][tk];
      o0 += s * vs[tk][dg];     o1 += s * vs[tk][dg + 1];
      o2 += s * vs[tk][dg + 2]; o3 += s * vs[tk][dg + 3];
    }
    float4* hp = (float4*)(h + base + (long long)tq * 1024 + dg);
    float4 hv = *hp;
    hv.x += o0; hv.y += o1; hv.z += o2; hv.w += o3;
    *hp = hv;                             // exclusive owner of this slice
  }
}

// ---------------------------------------------------------------------------
// Build patch matrix P bf16 [8704][192]; t=0 thumb = 2x2 avg (bilinear scale-4
// half-pixel), t=1+s patch; cols 147..191 zero-pad (K padded to 192).
// ---------------------------------------------------------------------------
__global__ void build_p(const float* __restrict__ x, u16* __restrict__ P)
{
  const int n = blockIdx.x;
  const int j = threadIdx.x;
  if (j >= 192) return;
  const int b = n / 17, t = n % 17;
  float val = 0.0f;
  if (j < 147) {
    const int c = j / 49, rem = j % 49, p = rem / 7, q = rem % 7;
    const float* xb = x + (long long)(b * 3 + c) * 784;
    if (t == 0) {
      const int r = 4 * p + 1, cc = 4 * q + 1;
      val = 0.25f * (xb[r * 28 + cc] + xb[r * 28 + cc + 1] +
                     xb[(r + 1) * 28 + cc] + xb[(r + 1) * 28 + cc + 1]);
    } else {
      const int s = t - 1, ii = s >> 2, jj = s & 3;
      val = xb[(7 * ii + p) * 28 + 7 * jj + q];
    }
  }
  P[(long long)n * 192 + j] = f2bf(val);
}

// conv_w fp32 [1024][147] -> Wc bf16 [1024][192] (zero-pad K to 192) and
// cw2 bf16 [256][1024]: cw2[j][c] = conv_w[c*147+j], rows 147..255 zero.
__global__ __launch_bounds__(256) void cvt_conv(const float* __restrict__ cw,
                                                u16* __restrict__ Wc, u16* __restrict__ cw2)
{
  const int i = blockIdx.x * 256 + threadIdx.x;     // grid covers 196608 + 262144
  if (i < 196608) {
    const int d = i / 192, j = i % 192;
    Wc[i] = (j < 147) ? f2bf(cw[d * 147 + j]) : (u16)0;
  } else {
    const int i2 = i - 196608;
    if (i2 < 262144) {
      const int j = i2 / 1024, c = i2 % 1024;
      cw2[i2] = (j < 147) ? f2bf(cw[c * 147 + j]) : (u16)0;
    }
  }
}

// W'[j][k] = sum_c cw2[j][c] * outw[c][k]  (fused out-proj+deconv weight).
__global__ __launch_bounds__(256) void wprime_kernel(
    const u16* __restrict__ cw2, const float* __restrict__ outw,
    u16* __restrict__ Wp)
{
  const int k = blockIdx.x * 256 + threadIdx.x;
  const int j = blockIdx.y;
  float a = 0.0f;
  for (int c = 0; c < 1024; ++c)
    a += bf2f(cw2[j * 1024 + c]) * outw[c * 1024 + k];
  Wp[j * 1024 + k] = f2bf(a);
}

// b'[j] = sum_c outb[c] * cw2[j][c]. One block, 256 threads.
__global__ __launch_bounds__(256) void bprime_kernel(
    const u16* __restrict__ cw2, const float* __restrict__ outb,
    float* __restrict__ bp)
{
  const int j = threadIdx.x;
  float a = 0.0f;
  for (int c = 0; c < 1024; ++c) a += outb[c] * bf2f(cw2[j * 1024 + c]);
  bp[j] = a;
}

// Bulk weight convert: 49 x 1M fp32 -> bf16.
__global__ __launch_bounds__(256) void cvt_all(
    const float* __restrict__ wq, const float* __restrict__ wk,
    const float* __restrict__ wv, const float* __restrict__ mlpw,
    const float* __restrict__ outw, u16* __restrict__ wAll)
{
  const int i = blockIdx.x * 256 + threadIdx.x;    // float4 index, < 12,845,056
  const int which = i >> 18;                        // 0..48
  const int off = i & 262143;
  const float4* src;
  if (which < 48) {
    const int layer = which >> 2, sub = which & 3;
    const float* base = (sub == 0) ? wq : (sub == 1) ? wk : (sub == 2) ? wv : mlpw;
    src = (const float4*)(base + (size_t)layer * 1048576) + off;
  } else {
    src = (const float4*)outw + off;
  }
  const float4 v = *src;
  ushort4 o; o.x = f2bf(v.x); o.y = f2bf(v.y); o.z = f2bf(v.z); o.w = f2bf(v.w);
  *(ushort4*)(wAll + (size_t)which * 1048576 + (size_t)off * 4) = o;
}

// per-layer weight cast fallback (small ws): wq,wk,wv -> o3[3][1M], mlp -> om.
__global__ __launch_bounds__(256) void cvt4(const float* __restrict__ a0, const float* __restrict__ a1,
                                            const float* __restrict__ a2, const float* __restrict__ a3,
                                            u16* __restrict__ o3, u16* __restrict__ om)
{
  const int i = blockIdx.x * 256 + threadIdx.x;
  const int which = i >> 20, off = i & 1048575;
  const float* src = (which == 0) ? a0 : (which == 1) ? a1 : (which == 2) ? a2 : a3;
  const float v = src[off];
  if (which < 3) o3[which * 1048576 + off] = f2bf(v);
  else           om[off] = f2bf(v);
}

__global__ __launch_bounds__(256) void cvtN(const float* __restrict__ in, u16* __restrict__ out, int n)
{
  const int i = blockIdx.x * 256 + threadIdx.x;
  if (i < n) out[i] = f2bf(in[i]);
}

// ---------------------------------------------------------------------------
extern "C" void kernel_launch(void* const* d_in, const int* in_sizes, int n_in,
                              void* d_out, int out_size, void* d_ws, size_t ws_size,
                              hipStream_t stream)
{
  const float* x     = (const float*)d_in[0];
  const float* convw = (const float*)d_in[1];
  const float* ln1w  = (const float*)d_in[2];
  const float* ln1b  = (const float*)d_in[3];
  const float* wq    = (const float*)d_in[4];
  const float* wk    = (const float*)d_in[5];
  const float* wv    = (const float*)d_in[6];
  const float* ln2w  = (const float*)d_in[7];
  const float* ln2b  = (const float*)d_in[8];
  const float* mlpw  = (const float*)d_in[9];
  const float* mlpb  = (const float*)d_in[10];
  const float* outw  = (const float*)d_in[11];
  const float* outb  = (const float*)d_in[12];

  char* w = (char*)d_ws;
  const bool big = (ws_size >= 214500352ULL);

  // swizzled grid sizes: 8 xcd * NZ * 9 groups * NX
  const int G_QKV = 8 * 3 * 9 * 8;   // 1728
  const int G_ONE = 8 * 1 * 9 * 8;   // 576
  const int G_DEC = 8 * 1 * 9 * 2;   // 144

  if (big) {
    float* h   = (float*)(w);                   // 35,651,584 B
    u16* Abuf  = (u16*)(w + 35651584);          // 17,825,792 B
    u16* QKV   = (u16*)(w + 53477376);          // 53,477,376 B (dead after last attn
                                                //   -> reused as bf16 h-shadow)
    u16* wAll  = (u16*)(w + 106954752);         // 102,760,448 B (49 x 1M bf16)
    u16* Wc    = (u16*)(w + 209715200);         //    393,216 B
    u16* cw2   = (u16*)(w + 210108416);         //    524,288 B
    u16* P     = (u16*)(w + 210632704);         //  3,342,336 B
    u16* Wp    = (u16*)(w + 213975040);         //    524,288 B
    float* bp  = (float*)(w + 214499328);       //      1,024 B -> 214,500,352

    cvt_all<<<50176, 256, 0, stream>>>(wq, wk, wv, mlpw, outw, wAll);
    cvt_conv<<<1792, 256, 0, stream>>>(convw, Wc, cw2);
    wprime_kernel<<<dim3(4, 256), 256, 0, stream>>>(cw2, outw, Wp);
    bprime_kernel<<<1, 256, 0, stream>>>(cw2, outb, bp);
    build_p<<<8704, 192, 0, stream>>>(x, P);
    gemm_bt<0><<<G_ONE, 256, 0, stream>>>(P, 192, Wc, Wc, Wc, 192, 192, 8,
                                          (void*)h, 0LL, 1024, nullptr);
    for (int l = 0; l < 12; ++l) {
      u16* wl = wAll + (size_t)l * 4194304;
      ln_kernel<<<8704, 256, 0, stream>>>(h, ln1w + l * 1024, ln1b + l * 1024, Abuf);
      gemm_bt<1><<<G_QKV, 256, 0, stream>>>(Abuf, 1024, wl, wl + 1048576, wl + 2097152,
                                            1024, 1024, 8, (void*)QKV, 8912896LL, 1024, nullptr);
      attn_kernel<<<8192, 256, 0, stream>>>(QKV, h);
      ln_kernel<<<8704, 256, 0, stream>>>(h, ln2w + l * 1024, ln2b + l * 1024, Abuf);
      if (l < 11) {
        gemm_bt<2><<<G_ONE, 256, 0, stream>>>(Abuf, 1024, wl + 3145728, wl, wl,
                                              1024, 1024, 8, (void*)h, 0LL, 1024, mlpb + l * 1024);
      } else {  // last MLP: h += v AND bf16 shadow into QKV (dead; NOT an input)
        gemm_bt<4><<<G_ONE, 256, 0, stream>>>(Abuf, 1024, wl + 3145728, wl, wl,
                                              1024, 1024, 8, (void*)h,
                                              (long long)(uintptr_t)QKV, 1024,
                                              mlpb + l * 1024);
      }
    }
    // fused out-proj+decode: d_out = scatter(h_bf16 @ W'^T + b')
    gemm_bt<3><<<G_DEC, 256, 0, stream>>>(QKV, 1024, Wp, Wp, Wp,
                                          1024, 1024, 2, d_out, 0LL, 0, bp);
  } else {
    if (ws_size < 119603200ULL) return;
    float* h   = (float*)(w);
    u16* Abuf  = (u16*)(w + 35651584);
    u16* QKV   = (u16*)(w + 53477376);
    u16* wb3   = (u16*)(w + 106954752);          // 6,291,456
    u16* wmb   = (u16*)(w + 113246208);          // 2,097,152
    u16* Wc    = (u16*)(w + 115343360);          //   393,216
    u16* cw2   = (u16*)(w + 115736576);          //   524,288
    u16* P     = (u16*)(w + 116260864);          // 3,342,336 -> 119,603,200

    cvt_conv<<<1792, 256, 0, stream>>>(convw, Wc, cw2);
    build_p<<<8704, 192, 0, stream>>>(x, P);
    gemm_bt<0><<<G_ONE, 256, 0, stream>>>(P, 192, Wc, Wc, Wc, 192, 192, 8,
                                          (void*)h, 0LL, 1024, nullptr);
    for (int l = 0; l < 12; ++l) {
      const size_t wo = (size_t)l * 1048576;
      cvt4<<<16384, 256, 0, stream>>>(wq + wo, wk + wo, wv + wo, mlpw + wo, wb3, wmb);
      ln_kernel<<<8704, 256, 0, stream>>>(h, ln1w + l * 1024, ln1b + l * 1024, Abuf);
      gemm_bt<1><<<G_QKV, 256, 0, stream>>>(Abuf, 1024, wb3, wb3 + 1048576, wb3 + 2097152,
                                            1024, 1024, 8, (void*)QKV, 8912896LL, 1024, nullptr);
      attn_kernel<<<8192, 256, 0, stream>>>(QKV, h);
      ln_kernel<<<8704, 256, 0, stream>>>(h, ln2w + l * 1024, ln2b + l * 1024, Abuf);
      gemm_bt<2><<<G_ONE, 256, 0, stream>>>(Abuf, 1024, wmb, wmb, wmb,
                                            1024, 1024, 8, (void*)h, 0LL, 1024, mlpb + l * 1024);
    }
    cvtN<<<34816, 256, 0, stream>>>(h, Abuf, 8912896);
    cvtN<<<4096, 256, 0, stream>>>(outw, wmb, 1048576);
    gemm_bt<1><<<G_ONE, 256, 0, stream>>>(Abuf, 1024, wmb, wmb, wmb,
                                          1024, 1024, 8, (void*)QKV, 0LL, 1024, outb);
    gemm_bt<3><<<G_DEC, 256, 0, stream>>>(QKV, 1024, cw2, cw2, cw2,
                                          1024, 1024, 2, d_out, 0LL, 0, nullptr);
  }
}